// Round 2
// baseline (568.675 us; speedup 1.0000x reference)
//
#include <hip/hip_runtime.h>
#include <hip/hip_bf16.h>

__device__ __forceinline__ float b2f(__hip_bfloat16 v) { return __bfloat162float(v); }

// Branched float load: isF32 ? fp32 : bf16 (flag is grid-uniform)
__device__ __forceinline__ float loadF(const void* p, long long i, int isF32) {
    if (isF32) return ((const float*)p)[i];
    return b2f(((const __hip_bfloat16*)p)[i]);
}

// Branched edge fetch: i64 => [2,E] int64 read as int32 pairs (LE: low word first)
__device__ __forceinline__ void get_edge(const int* ei, int i64, int e, int E, int& s, int& d) {
    if (i64) { s = ei[2 * (long long)e]; d = ei[2 * (long long)E + 2 * (long long)e]; }
    else     { s = ei[e];                d = ei[(long long)E + e]; }
}

// ---- dtype detection: flags[0]=1 if floats are fp32; flags[1]=1 if indices are int64 ----
__global__ void k_detect(const void* x, const int* ei, int* flags) {
    __shared__ int s_sane, s_zero;
    int tid = threadIdx.x;
    if (tid == 0) { s_sane = 0; s_zero = 0; }
    __syncthreads();
    const unsigned short* xu = (const unsigned short*)x;
    int sane = 0;
    for (int k = tid; k < 4096; k += 256) {
        unsigned int bits = ((unsigned int)xu[2 * k]) << 16;  // even bf16 slot
        float v = __uint_as_float(bits);
        float a = fabsf(v);
        if (v == 0.0f || (a >= 9.3e-10f && a <= 1.1e9f)) sane++;
    }
    atomicAdd(&s_sane, sane);
    int zero = 0;
    for (int k = tid; k < 1024; k += 256) {
        if (ei[2 * k + 1] == 0) zero++;  // odd int32 word: int64 high half would be 0
    }
    atomicAdd(&s_zero, zero);
    __syncthreads();
    if (tid == 0) {
        flags[0] = (s_sane < 3000) ? 1 : 0;  // bf16 memory => ~4096 sane; fp32 => ~1000
        flags[1] = (s_zero > 512) ? 1 : 0;
    }
}

// ---- convert weights to fp32 in ws: W1f[4096] b1f[64] W2f[1024] b2f[16] ----
__global__ void k_prep(const void* W1, const void* b1, const void* W2, const void* b2,
                       const int* flags, float* Wbuf) {
    int f = flags[0];
    int tid = threadIdx.x;
    for (int i = tid; i < 4096; i += 256) Wbuf[i] = loadF(W1, i, f);
    if (tid < 64) Wbuf[4096 + tid] = loadF(b1, tid, f);
    for (int i = tid; i < 1024; i += 256) Wbuf[4160 + i] = loadF(W2, i, f);
    if (tid < 16) Wbuf[5184 + tid] = loadF(b2, tid, f);
}

// ---- degree count: deg[src[e]] += 1 ----
__global__ void k_count(const int* __restrict__ ei, const int* __restrict__ flags,
                        int E, float* __restrict__ deg) {
    int e = blockIdx.x * blockDim.x + threadIdx.x;
    if (e < E) {
        int s, d;
        get_edge(ei, flags[1], e, E, s, d);
        atomicAdd(&deg[s], 1.0f);
    }
}

// ---- dis[i] = rsqrt(deg[i] + 1)  (self loop) ----
__global__ void k_dis(float* __restrict__ deg, int N) {
    int i = blockIdx.x * blockDim.x + threadIdx.x;
    if (i < N) deg[i] = rsqrtf(deg[i] + 1.0f);
}

// ---- A[i][j] = dis[i]^2 * x[i][j]  (self-loop contribution = init, no memset) ----
__global__ void k_initA(const void* __restrict__ x, const int* __restrict__ flags,
                        const float* __restrict__ dis, float* __restrict__ A, int N) {
    int f = flags[0];
    long long t = (long long)blockIdx.x * blockDim.x + threadIdx.x;
    if (t < (long long)N * 64) {
        int i = (int)(t >> 6);
        float d = dis[i];
        A[t] = d * d * loadF(x, t, f);
    }
}

// ---- A[dst] += dis[s]*dis[d] * x[src], 64 lanes per edge ----
__global__ void k_aggr1(const int* __restrict__ ei, const int* __restrict__ flags,
                        const void* __restrict__ x, const float* __restrict__ dis,
                        float* __restrict__ A, int E) {
    int f = flags[0], fi = flags[1];
    long long t = (long long)blockIdx.x * blockDim.x + threadIdx.x;
    int e = (int)(t >> 6);
    int j = (int)(t & 63);
    if (e < E) {
        int s, d;
        get_edge(ei, fi, e, E, s, d);
        float nrm = dis[s] * dis[d];
        atomicAdd(&A[(long long)d * 64 + j], nrm * loadF(x, (long long)s * 64 + j, f));
    }
}

// ---- fused: h = relu(A@W1+b1) (LDS only); T2 = h@W2 ----
__global__ __launch_bounds__(256) void k_gemm12(const float* __restrict__ A,
                                                const float* __restrict__ Wbuf,
                                                float* __restrict__ T2, int N) {
    __shared__ float Ws[64 * 64];
    __shared__ float W2s[64 * 16];
    __shared__ float xs[4 * 64];
    __shared__ float hs[4 * 64];
    __shared__ float bs[64];
    int tid = threadIdx.x;
    for (int i = tid; i < 4096; i += 256) Ws[i] = Wbuf[i];
    if (tid < 64) bs[tid] = Wbuf[4096 + tid];
    for (int i = tid; i < 1024; i += 256) W2s[i] = Wbuf[4160 + i];
    int n0 = blockIdx.x * 4;
    int ln = tid >> 6, j = tid & 63;
    int n = n0 + ln;
    xs[tid] = (n < N) ? A[(long long)n * 64 + j] : 0.0f;
    __syncthreads();
    float acc = bs[j];
#pragma unroll
    for (int k = 0; k < 64; ++k) acc += xs[ln * 64 + k] * Ws[k * 64 + j];
    hs[tid] = fmaxf(acc, 0.0f);
    __syncthreads();
    if (tid < 64) {
        int l2 = tid >> 4, j2 = tid & 15;
        int n2 = n0 + l2;
        if (n2 < N) {
            float a2 = 0.0f;
#pragma unroll
            for (int k = 0; k < 64; ++k) a2 += hs[l2 * 64 + k] * W2s[k * 16 + j2];
            T2[(long long)n2 * 16 + j2] = a2;
        }
    }
}

// ---- O[i][j] = dis[i]^2 * T2[i][j] ----
__global__ void k_initO(const float* __restrict__ T2, const float* __restrict__ dis,
                        float* __restrict__ O, int N) {
    long long t = (long long)blockIdx.x * blockDim.x + threadIdx.x;
    if (t < (long long)N * 16) {
        int i = (int)(t >> 4);
        float d = dis[i];
        O[t] = d * d * T2[t];
    }
}

// ---- O[dst] += dis[s]*dis[d] * T2[src], 16 lanes per edge ----
__global__ void k_aggr2(const int* __restrict__ ei, const int* __restrict__ flags,
                        const float* __restrict__ T2, const float* __restrict__ dis,
                        float* __restrict__ O, int E) {
    int fi = flags[1];
    long long t = (long long)blockIdx.x * blockDim.x + threadIdx.x;
    int e = (int)(t >> 4);
    int j = (int)(t & 15);
    if (e < E) {
        int s, d;
        get_edge(ei, fi, e, E, s, d);
        float nrm = dis[s] * dis[d];
        atomicAdd(&O[(long long)d * 16 + j], nrm * T2[(long long)s * 16 + j]);
    }
}

// ---- out = log_softmax(O + b2), 16 lanes per node; output dtype branched ----
__global__ void k_final(const float* __restrict__ O, const float* __restrict__ Wbuf,
                        void* __restrict__ out, const int* __restrict__ flags, int N) {
    int isF32 = flags[0];
    int tid = threadIdx.x;
    int n = blockIdx.x * 16 + (tid >> 4);
    int j = tid & 15;
    if (n >= N) return;
    float v = O[(long long)n * 16 + j] + Wbuf[5184 + j];
    float m = v;
#pragma unroll
    for (int off = 8; off; off >>= 1) m = fmaxf(m, __shfl_xor(m, off, 16));
    float ex = __expf(v - m);
    float ssum = ex;
#pragma unroll
    for (int off = 8; off; off >>= 1) ssum += __shfl_xor(ssum, off, 16);
    float r = v - m - logf(ssum);
    long long idx = (long long)n * 16 + j;
    if (isF32) ((float*)out)[idx] = r;
    else       ((__hip_bfloat16*)out)[idx] = __float2bfloat16(r);
}

extern "C" void kernel_launch(void* const* d_in, const int* in_sizes, int n_in,
                              void* d_out, int out_size, void* d_ws, size_t ws_size,
                              hipStream_t stream) {
    const void* x  = d_in[0];
    const int*  ei = (const int*)d_in[1];
    const void* W1 = d_in[2];
    const void* b1 = d_in[3];
    const void* W2 = d_in[4];
    const void* b2 = d_in[5];

    const int N = in_sizes[0] / 64;   // 100000
    const int E = in_sizes[1] / 2;    // 1200000 (element count / 2, width-agnostic)

    // ws layout (floats): dis[N] | A[64N] | T2[16N] | Wbuf[5200] | flags[2 ints]
    // O aliases A[0:16N] (A is dead after k_gemm12). Total ~32.4 MB.
    float* dis  = (float*)d_ws;
    float* A    = dis + N;
    float* T2   = A + (size_t)N * 64;
    float* Wbuf = T2 + (size_t)N * 16;
    int*   flags = (int*)(Wbuf + 5200);
    float* O    = A;  // 16N floats, reuses dead A

    k_detect<<<1, 256, 0, stream>>>(x, ei, flags);
    k_prep<<<1, 256, 0, stream>>>(W1, b1, W2, b2, flags, Wbuf);
    hipMemsetAsync(dis, 0, (size_t)N * sizeof(float), stream);
    k_count<<<(E + 255) / 256, 256, 0, stream>>>(ei, flags, E, dis);
    k_dis<<<(N + 255) / 256, 256, 0, stream>>>(dis, N);
    k_initA<<<(int)(((long long)N * 64 + 255) / 256), 256, 0, stream>>>(x, flags, dis, A, N);
    k_aggr1<<<(int)(((long long)E * 64 + 255) / 256), 256, 0, stream>>>(ei, flags, x, dis, A, E);
    k_gemm12<<<(N + 3) / 4, 256, 0, stream>>>(A, Wbuf, T2, N);
    k_initO<<<(int)(((long long)N * 16 + 255) / 256), 256, 0, stream>>>(T2, dis, O, N);
    k_aggr2<<<(int)(((long long)E * 16 + 255) / 256), 256, 0, stream>>>(ei, flags, T2, dis, O, E);
    k_final<<<(N + 15) / 16, 256, 0, stream>>>(O, Wbuf, d_out, flags, N);
}